// Round 2
// baseline (75.878 us; speedup 1.0000x reference)
//
#include <hip/hip_runtime.h>
#include <hip/hip_cooperative_groups.h>

namespace cg = cooperative_groups;

#define NN 1024
#define DIM 64
#define NB 64        // blocks; 16 rows each

// One fused cooperative kernel:
//  phase1: row pos/neg sums of graph -> base (regs), u1=relu(base) (regs),
//          per-block column partials -> pA
//  rounds 2..4: grid.sync; summ = sum(partials); qs = W2@summ;
//          u' = relu(base + qs - W2@u) (u rows staged in LDS); new partials
//  final: grid.sync; block 0: su, h1/h2, dot with W5 -> out
__global__ __launch_bounds__(256) void s2v_fused(
    const float* __restrict__ x, const float* __restrict__ graph,
    const float* __restrict__ W1, const float* __restrict__ W2,
    const float* __restrict__ W3, const float* __restrict__ W4,
    const float* __restrict__ W5, const float* __restrict__ W6,
    const float* __restrict__ W7, const int* __restrict__ vptr,
    float* __restrict__ out,
    float* __restrict__ pA, float* __restrict__ pB, float* __restrict__ uvg)
{
    cg::grid_group grid = cg::this_grid();

    __shared__ float w2t[DIM * 65];     // w2t[e*65+d] = W2[d,e]; pad -> 2-way bank alias (free)
    __shared__ float uloc[16 * DIM];    // this block's 16 rows of u
    __shared__ float sparts[4 * DIM];
    __shared__ float summ[DIM], qs[DIM];
    __shared__ float pcol[4][DIM];
    __shared__ float ppos[16], pneg[16];
    __shared__ float c1[DIM], c2[DIM], w4s[DIM];

    const int t = threadIdx.x, lane = t & 63, wave = t >> 6;
    const int b = blockIdx.x;
    const int v = vptr[0];

    // ---- W2 transposed into LDS ----
    #pragma unroll
    for (int k = 0; k < 16; ++k) {
        const int idx = t + 256 * k;
        w2t[(idx & 63) * 65 + (idx >> 6)] = W2[idx];
    }
    if (t < DIM) w4s[t] = W4[t];
    __syncthreads();

    // ---- per-row pos/neg sums of graph (wave w: rows w*4+p) ----
    for (int p = 0; p < 4; ++p) {
        const int rloc = wave * 4 + p;
        const float* row = graph + (size_t)(b * 16 + rloc) * NN;
        float pos = 0.f, neg = 0.f;
        #pragma unroll
        for (int k = 0; k < 4; ++k) {
            float4 g = *reinterpret_cast<const float4*>(row + 4 * lane + 256 * k);
            pos += fmaxf(g.x,0.f)+fmaxf(g.y,0.f)+fmaxf(g.z,0.f)+fmaxf(g.w,0.f);
            neg += fminf(g.x,0.f)+fminf(g.y,0.f)+fminf(g.z,0.f)+fminf(g.w,0.f);
        }
        #pragma unroll
        for (int m = 32; m >= 1; m >>= 1) {
            pos += __shfl_xor(pos, m, 64);
            neg += __shfl_xor(neg, m, 64);
        }
        if (lane == 0) { ppos[rloc] = pos; pneg[rloc] = neg; }
    }
    // c1 = W3 @ relu(W4); c2 = W3 @ min(W4,0)
    if (t < DIM) {
        float a1 = 0.f, a2 = 0.f;
        const float* w3r = W3 + t * DIM;
        #pragma unroll 8
        for (int e = 0; e < DIM; ++e) {
            a1 += w3r[e] * fmaxf(w4s[e], 0.f);
            a2 += w3r[e] * fminf(w4s[e], 0.f);
        }
        c1[t] = a1; c2[t] = a2;
    }
    __syncthreads();

    // ---- base & u1 in registers; stage uloc; partials -> pA ----
    float br[4], ur[4];
    {
        const float w1l = W1[lane];
        float pacc = 0.f;
        #pragma unroll
        for (int p = 0; p < 4; ++p) {
            const int rloc = wave * 4 + p;
            const int i = b * 16 + rloc;
            br[p] = x[i] * w1l + ppos[rloc] * c1[lane] + pneg[rloc] * c2[lane];
            ur[p] = fmaxf(br[p], 0.f);
            uloc[rloc * DIM + lane] = ur[p];
            pacc += ur[p];
        }
        pcol[wave][lane] = pacc;
    }
    __syncthreads();
    if (t < DIM) pA[b * DIM + t] = pcol[0][t] + pcol[1][t] + pcol[2][t] + pcol[3][t];

    // ---- rounds 2..4 ----
    float* pSrc = pA;
    float* pDst = pB;
    for (int r = 0; r < 3; ++r) {
        grid.sync();
        {   // reduce 64 blocks' partials
            float s = 0.f;
            #pragma unroll
            for (int k = 0; k < 16; ++k)
                s += pSrc[(wave + 4 * k) * DIM + lane];
            sparts[wave * DIM + lane] = s;
        }
        __syncthreads();
        if (t < DIM)
            summ[t] = sparts[t] + sparts[DIM+t] + sparts[2*DIM+t] + sparts[3*DIM+t];
        __syncthreads();
        if (t < DIM) {
            float q = 0.f;
            #pragma unroll 8
            for (int e = 0; e < DIM; ++e) q += w2t[e * 65 + t] * summ[e];
            qs[t] = q;
        }
        __syncthreads();

        float pacc = 0.f;
        #pragma unroll
        for (int p = 0; p < 4; ++p) {
            const int rloc = wave * 4 + p;
            float acc = 0.f;
            #pragma unroll 8
            for (int e = 0; e < DIM; ++e)
                acc += w2t[e * 65 + lane] * uloc[rloc * DIM + e];
            ur[p] = fmaxf(br[p] + qs[lane] - acc, 0.f);
            pacc += ur[p];
        }
        __syncthreads();
        #pragma unroll
        for (int p = 0; p < 4; ++p)
            uloc[(wave * 4 + p) * DIM + lane] = ur[p];
        pcol[wave][lane] = pacc;
        __syncthreads();
        if (t < DIM) pDst[b * DIM + t] = pcol[0][t] + pcol[1][t] + pcol[2][t] + pcol[3][t];
        float* tmp = pSrc; pSrc = pDst; pDst = tmp;
    }
    // pSrc now holds round-4 partials

    // ---- publish u4[v] ----
    if (b == (v >> 4)) {
        const int rloc = v & 15;
        if (wave == (rloc >> 2)) uvg[lane] = ur[rloc & 3];
    }
    grid.sync();

    // ---- final: block 0 ----
    if (b == 0) {
        __shared__ float su[DIM], uv[DIM];
        if (t < DIM) {
            float s = 0.f;
            #pragma unroll 8
            for (int bb = 0; bb < NB; ++bb) s += pSrc[bb * DIM + t];
            su[t] = s;
            uv[t] = uvg[t];
        }
        __syncthreads();
        if (t < DIM) {
            float h1 = 0.f, h2 = 0.f;
            const float* w6r = W6 + t * DIM;
            const float* w7r = W7 + t * DIM;
            #pragma unroll 8
            for (int e = 0; e < DIM; ++e) {
                h1 += w6r[e] * su[e];
                h2 += w7r[e] * uv[e];
            }
            float val = W5[t] * fmaxf(h1, 0.f) + W5[DIM + t] * fmaxf(h2, 0.f);
            #pragma unroll
            for (int m = 32; m >= 1; m >>= 1) val += __shfl_xor(val, m, 64);
            if (t == 0) out[0] = val;
        }
    }
}

extern "C" void kernel_launch(void* const* d_in, const int* in_sizes, int n_in,
                              void* d_out, int out_size, void* d_ws, size_t ws_size,
                              hipStream_t stream) {
    const float* x     = (const float*)d_in[0];
    const float* graph = (const float*)d_in[1];
    const float* W1    = (const float*)d_in[2];
    const float* W2    = (const float*)d_in[3];
    const float* W3    = (const float*)d_in[4];
    const float* W4    = (const float*)d_in[5];
    const float* W5    = (const float*)d_in[6];
    const float* W6    = (const float*)d_in[7];
    const float* W7    = (const float*)d_in[8];
    const int*   vptr  = (const int*)d_in[9];
    float* out = (float*)d_out;

    float* ws  = (float*)d_ws;
    float* pA  = ws;                  // 64*64 f32
    float* pB  = ws + NB * DIM;       // 64*64 f32
    float* uvg = ws + 2 * NB * DIM;   // 64 f32

    void* args[] = { (void*)&x, (void*)&graph, (void*)&W1, (void*)&W2,
                     (void*)&W3, (void*)&W4, (void*)&W5, (void*)&W6,
                     (void*)&W7, (void*)&vptr, (void*)&out,
                     (void*)&pA, (void*)&pB, (void*)&uvg };
    hipLaunchCooperativeKernel((const void*)s2v_fused, dim3(NB), dim3(256),
                               args, 0, stream);
}

// Round 3
// 42.041 us; speedup vs baseline: 1.8048x; 1.8048x over previous
//
#include <hip/hip_runtime.h>

#define NN 1024
#define DIM 64
#define NB 64      // blocks, 16 rows each
#define NT 512     // 8 waves

typedef unsigned long long u64;

__device__ __forceinline__ u64 pack2(float a, float b) {
    union { float f[2]; u64 u; } c; c.f[0] = a; c.f[1] = b; return c.u;
}
__device__ __forceinline__ void unpack2(u64 v, float& a, float& b) {
    union { u64 u; float f[2]; } c; c.u = v; a = c.f[0]; b = c.f[1];
}

// per-stage grid barrier: counter at ctr[stage*16] (64B apart), zeroed by memset each call
__device__ __forceinline__ void gbar(unsigned* ctr, int stage) {
    __syncthreads();                       // drains vmem (slot stores) before arrive
    if (threadIdx.x == 0) {
        unsigned* c = ctr + stage * 16;
        __hip_atomic_fetch_add(c, 1u, __ATOMIC_RELEASE, __HIP_MEMORY_SCOPE_AGENT);
        while (__hip_atomic_load(c, __ATOMIC_RELAXED, __HIP_MEMORY_SCOPE_AGENT) < (unsigned)NB)
            __builtin_amdgcn_s_sleep(2);
        (void)__hip_atomic_load(c, __ATOMIC_ACQUIRE, __HIP_MEMORY_SCOPE_AGENT);
    }
    __syncthreads();
}

__global__ __launch_bounds__(NT) void s2v_one(
    const float* __restrict__ x, const float* __restrict__ graph,
    const float* __restrict__ W1, const float* __restrict__ W2,
    const float* __restrict__ W3, const float* __restrict__ W4,
    const float* __restrict__ W5, const float* __restrict__ W6,
    const float* __restrict__ W7, const int* __restrict__ vptr,
    float* __restrict__ out,
    unsigned* __restrict__ ctr,      // 4 counters, 64 B apart
    u64* __restrict__ slots,         // [4][NB][32] packed partials
    u64* __restrict__ uvg)           // [32] packed u4[v]
{
    __shared__ float w2t[DIM * 65];     // w2t[e*65+d] = W2[d,e]
    __shared__ float uloc[16 * DIM];
    __shared__ float summ[DIM], qs[DIM];
    __shared__ float pcol[8][DIM];
    __shared__ float ppos[16], pneg[16];
    __shared__ float c1s[DIM], c2s[DIM], w4s[DIM];
    __shared__ float su[DIM], uv[DIM];

    const int t = threadIdx.x, lane = t & 63, wave = t >> 6;
    const int b = blockIdx.x;
    const int v = vptr[0];

    // ---- W2^T into LDS (4096 elems / 512 thr = 8 each) ----
    #pragma unroll
    for (int k = 0; k < 8; ++k) {
        const int idx = t + NT * k;
        w2t[(idx & 63) * 65 + (idx >> 6)] = W2[idx];
    }
    if (t < DIM) w4s[t] = W4[t];
    __syncthreads();

    // ---- per-row pos/neg sums of graph: wave w -> rows 2w, 2w+1 ----
    #pragma unroll
    for (int p = 0; p < 2; ++p) {
        const int rloc = wave * 2 + p;
        const float* row = graph + (size_t)(b * 16 + rloc) * NN;
        float pos = 0.f, neg = 0.f;
        #pragma unroll
        for (int k = 0; k < 4; ++k) {
            float4 g = *reinterpret_cast<const float4*>(row + 4 * lane + 256 * k);
            pos += fmaxf(g.x,0.f)+fmaxf(g.y,0.f)+fmaxf(g.z,0.f)+fmaxf(g.w,0.f);
            neg += fminf(g.x,0.f)+fminf(g.y,0.f)+fminf(g.z,0.f)+fminf(g.w,0.f);
        }
        #pragma unroll
        for (int m = 32; m >= 1; m >>= 1) {
            pos += __shfl_xor(pos, m, 64);
            neg += __shfl_xor(neg, m, 64);
        }
        if (lane == 0) { ppos[rloc] = pos; pneg[rloc] = neg; }
    }
    // c1 = W3 @ relu(W4); c2 = W3 @ min(W4,0)
    if (t < DIM) {
        float a1 = 0.f, a2 = 0.f;
        const float* w3r = W3 + t * DIM;
        #pragma unroll 8
        for (int e = 0; e < DIM; ++e) {
            a1 += w3r[e] * fmaxf(w4s[e], 0.f);
            a2 += w3r[e] * fminf(w4s[e], 0.f);
        }
        c1s[t] = a1; c2s[t] = a2;
    }
    __syncthreads();

    // ---- base & u1 in regs; stage uloc; column partials ----
    float br[2], ur[2];
    const float w1l = W1[lane];
    {
        float pacc = 0.f;
        #pragma unroll
        for (int p = 0; p < 2; ++p) {
            const int rloc = wave * 2 + p;
            const int i = b * 16 + rloc;
            br[p] = x[i] * w1l + ppos[rloc] * c1s[lane] + pneg[rloc] * c2s[lane];
            ur[p] = fmaxf(br[p], 0.f);
            uloc[rloc * DIM + lane] = ur[p];
            pacc += ur[p];
        }
        pcol[wave][lane] = pacc;
    }
    __syncthreads();

    // publish stage-0 partials (wave 0): pack pairs, relaxed agent atomic stores
    {
        float ps = 0.f;
        if (wave == 0) {
            #pragma unroll
            for (int w = 0; w < 8; ++w) ps += pcol[w][lane];
        }
        if (wave == 0) {
            const float lo = __shfl(ps, 2 * (lane & 31), 64);
            const float hi = __shfl(ps, 2 * (lane & 31) + 1, 64);
            if (lane < 32)
                __hip_atomic_store(&slots[(size_t)(0 * NB + b) * 32 + lane],
                                   pack2(lo, hi), __ATOMIC_RELAXED, __HIP_MEMORY_SCOPE_AGENT);
        }
    }
    gbar(ctr, 0);

    // ---- rounds 2..4 ----
    for (int r = 0; r < 3; ++r) {
        // summ from stage-r slots (fixed order -> deterministic)
        if (wave == 0 && lane < 32) {
            float a0 = 0.f, a1 = 0.f;
            #pragma unroll 8
            for (int j = 0; j < NB; ++j) {
                u64 pv = __hip_atomic_load(&slots[(size_t)(r * NB + j) * 32 + lane],
                                           __ATOMIC_RELAXED, __HIP_MEMORY_SCOPE_AGENT);
                float f0, f1; unpack2(pv, f0, f1);
                a0 += f0; a1 += f1;
            }
            summ[2 * lane] = a0; summ[2 * lane + 1] = a1;
        }
        __syncthreads();
        if (t < DIM) {
            float q = 0.f;
            #pragma unroll 8
            for (int e = 0; e < DIM; ++e) q += w2t[e * 65 + t] * summ[e];
            qs[t] = q;
        }
        __syncthreads();

        // u' = relu(base + qs - W2 @ u)
        float pacc = 0.f;
        #pragma unroll
        for (int p = 0; p < 2; ++p) {
            const int rloc = wave * 2 + p;
            float acc = 0.f;
            #pragma unroll 8
            for (int e = 0; e < DIM; ++e)
                acc += w2t[e * 65 + lane] * uloc[rloc * DIM + e];
            ur[p] = fmaxf(br[p] + qs[lane] - acc, 0.f);
            pacc += ur[p];
        }
        // wave-local rows: safe to overwrite after the reads above (lockstep wave)
        #pragma unroll
        for (int p = 0; p < 2; ++p)
            uloc[(wave * 2 + p) * DIM + lane] = ur[p];
        pcol[wave][lane] = pacc;
        __syncthreads();

        // publish stage r+1
        if (wave == 0) {
            float ps = 0.f;
            #pragma unroll
            for (int w = 0; w < 8; ++w) ps += pcol[w][lane];
            const float lo = __shfl(ps, 2 * (lane & 31), 64);
            const float hi = __shfl(ps, 2 * (lane & 31) + 1, 64);
            if (lane < 32)
                __hip_atomic_store(&slots[(size_t)((r + 1) * NB + b) * 32 + lane],
                                   pack2(lo, hi), __ATOMIC_RELAXED, __HIP_MEMORY_SCOPE_AGENT);
        }
        // on the last round, owner block publishes u4[v]
        if (r == 2 && b == (v >> 4)) {
            const int rloc = v & 15;
            if (wave == (rloc >> 1)) {
                const float uval = ur[rloc & 1];
                const float lo = __shfl(uval, 2 * (lane & 31), 64);
                const float hi = __shfl(uval, 2 * (lane & 31) + 1, 64);
                if (lane < 32)
                    __hip_atomic_store(&uvg[lane], pack2(lo, hi),
                                       __ATOMIC_RELAXED, __HIP_MEMORY_SCOPE_AGENT);
            }
        }
        gbar(ctr, r + 1);
    }

    // ---- final: block 0 ----
    if (b == 0) {
        if (wave == 0 && lane < 32) {
            float a0 = 0.f, a1 = 0.f;
            #pragma unroll 8
            for (int j = 0; j < NB; ++j) {
                u64 pv = __hip_atomic_load(&slots[(size_t)(3 * NB + j) * 32 + lane],
                                           __ATOMIC_RELAXED, __HIP_MEMORY_SCOPE_AGENT);
                float f0, f1; unpack2(pv, f0, f1);
                a0 += f0; a1 += f1;
            }
            su[2 * lane] = a0; su[2 * lane + 1] = a1;
            u64 uvv = __hip_atomic_load(&uvg[lane], __ATOMIC_RELAXED, __HIP_MEMORY_SCOPE_AGENT);
            float f0, f1; unpack2(uvv, f0, f1);
            uv[2 * lane] = f0; uv[2 * lane + 1] = f1;
        }
        __syncthreads();
        if (t < DIM) {
            float h1 = 0.f, h2 = 0.f;
            const float* w6r = W6 + t * DIM;
            const float* w7r = W7 + t * DIM;
            #pragma unroll 8
            for (int e = 0; e < DIM; ++e) {
                h1 += w6r[e] * su[e];
                h2 += w7r[e] * uv[e];
            }
            float val = W5[t] * fmaxf(h1, 0.f) + W5[DIM + t] * fmaxf(h2, 0.f);
            #pragma unroll
            for (int m = 32; m >= 1; m >>= 1) val += __shfl_xor(val, m, 64);
            if (t == 0) out[0] = val;
        }
    }
}

extern "C" void kernel_launch(void* const* d_in, const int* in_sizes, int n_in,
                              void* d_out, int out_size, void* d_ws, size_t ws_size,
                              hipStream_t stream) {
    const float* x     = (const float*)d_in[0];
    const float* graph = (const float*)d_in[1];
    const float* W1    = (const float*)d_in[2];
    const float* W2    = (const float*)d_in[3];
    const float* W3    = (const float*)d_in[4];
    const float* W4    = (const float*)d_in[5];
    const float* W5    = (const float*)d_in[6];
    const float* W6    = (const float*)d_in[7];
    const float* W7    = (const float*)d_in[8];
    const int*   vptr  = (const int*)d_in[9];
    float* out = (float*)d_out;

    unsigned char* ws = (unsigned char*)d_ws;
    unsigned* ctr = (unsigned*)ws;                       // 256 B (4 counters, 64 B apart)
    u64* slots    = (u64*)(ws + 1024);                   // 4*64*32*8 = 64 KB
    u64* uvg      = (u64*)(ws + 1024 + 4 * NB * 32 * 8); // 256 B

    hipMemsetAsync(ctr, 0, 256, stream);
    s2v_one<<<NB, NT, 0, stream>>>(x, graph, W1, W2, W3, W4, W5, W6, W7,
                                   vptr, out, ctr, slots, uvg);
}

// Round 4
// 23.934 us; speedup vs baseline: 3.1703x; 1.7566x over previous
//
#include <hip/hip_runtime.h>

#define NN 1024
#define DIM 64
#define NB 128     // blocks; 8 rows each; wave w owns global row b*8+w
#define NT 512     // 8 waves

typedef unsigned int u32;

// per-stage sense tags (≠ 0xAAAAAAAA poison, ≠ each other, ≠ prior-replay leftovers)
#define S1 0x51F0A001u
#define S2 0x51F0A002u
#define S3 0x51F0A003u
#define S4 0x51F0A004u

// agent-scope relaxed atomics: sc1-coherent (cross-XCD) with NO cache maintenance
__device__ __forceinline__ void slot_store(u32* p, float v) {
    union { float f; u32 u; } c; c.f = v;
    __hip_atomic_store(p, c.u, __ATOMIC_RELAXED, __HIP_MEMORY_SCOPE_AGENT);
}
__device__ __forceinline__ float slot_load(const u32* p) {
    union { u32 u; float f; } c;
    c.u = __hip_atomic_load(p, __ATOMIC_RELAXED, __HIP_MEMORY_SCOPE_AGENT);
    return c.f;
}
__device__ __forceinline__ u32 flag_load(const u32* p) {
    return __hip_atomic_load(p, __ATOMIC_RELAXED, __HIP_MEMORY_SCOPE_AGENT);
}
__device__ __forceinline__ void flag_store(u32* p, u32 v) {
    __hip_atomic_store(p, v, __ATOMIC_RELAXED, __HIP_MEMORY_SCOPE_AGENT);
}

// all 64 lanes of wave 0 poll the 128 per-block flags (stride 16 u32 = 64 B)
__device__ __forceinline__ void poll_all(const u32* flags, u32 sense, int lane) {
    for (;;) {
        const u32 v0 = flag_load(&flags[lane * 16]);
        const u32 v1 = flag_load(&flags[(64 + lane) * 16]);
        if (__all((v0 == sense) && (v1 == sense))) break;
        __builtin_amdgcn_s_sleep(1);
    }
}

__global__ __launch_bounds__(NT) void s2v(
    const float* __restrict__ x, const float* __restrict__ graph,
    const float* __restrict__ W1, const float* __restrict__ W2,
    const float* __restrict__ W3, const float* __restrict__ W4,
    const float* __restrict__ W5, const float* __restrict__ W6,
    const float* __restrict__ W7, const int* __restrict__ vptr,
    float* __restrict__ out,
    u32* __restrict__ flagA, u32* __restrict__ flagB,
    u32* __restrict__ slots,        // [4][NB][DIM] f32-as-u32
    u32* __restrict__ uvg)          // [DIM]
{
    __shared__ float w2t[DIM * 65];        // w2t[e*65+d] = W2[d*DIM+e]
    __shared__ float uloc[8 * DIM];        // this block's 8 rows of u
    __shared__ float part[8][DIM];         // per-wave partial of summ
    __shared__ float part2[8][DIM];        // per-wave partial of qs
    __shared__ float pcol[8][DIM];         // per-row u for block partial
    __shared__ float w4s[DIM], c1s[DIM], c2s[DIM];
    __shared__ float su[DIM], uv[DIM];

    const int t = threadIdx.x, lane = t & 63, wave = t >> 6;
    const int b = blockIdx.x;
    const int v = vptr[0];

    // ---- W2^T into LDS; W4 into LDS ----
    #pragma unroll
    for (int k = 0; k < 8; ++k) {
        const int idx = t + NT * k;
        w2t[(idx & 63) * 65 + (idx >> 6)] = W2[idx];
    }
    if (t < DIM) w4s[t] = W4[t];
    __syncthreads();

    // ---- row pos/neg sums of graph: wave w -> row b*8+w; result in regs ----
    float pos = 0.f, neg = 0.f;
    {
        const float* row = graph + (size_t)(b * 8 + wave) * NN;
        #pragma unroll
        for (int k = 0; k < 4; ++k) {
            float4 g = *reinterpret_cast<const float4*>(row + 4 * lane + 256 * k);
            pos += fmaxf(g.x,0.f)+fmaxf(g.y,0.f)+fmaxf(g.z,0.f)+fmaxf(g.w,0.f);
            neg += fminf(g.x,0.f)+fminf(g.y,0.f)+fminf(g.z,0.f)+fminf(g.w,0.f);
        }
        #pragma unroll
        for (int m = 32; m >= 1; m >>= 1) {
            pos += __shfl_xor(pos, m, 64);
            neg += __shfl_xor(neg, m, 64);
        }
    }
    // c1 = W3 @ relu(W4); c2 = W3 @ min(W4,0)
    if (t < DIM) {
        float a1 = 0.f, a2 = 0.f;
        const float* w3r = W3 + t * DIM;
        #pragma unroll 8
        for (int e = 0; e < DIM; ++e) {
            a1 += w3r[e] * fmaxf(w4s[e], 0.f);
            a2 += w3r[e] * fminf(w4s[e], 0.f);
        }
        c1s[t] = a1; c2s[t] = a2;
    }
    __syncthreads();

    // ---- base & u1 (scalars per thread: one row per wave) ----
    float br, ur;
    {
        const float xv = x[b * 8 + wave];
        br = xv * W1[lane] + pos * c1s[lane] + neg * c2s[lane];
        ur = fmaxf(br, 0.f);
        uloc[wave * DIM + lane] = ur;
        pcol[wave][lane] = ur;
    }
    __syncthreads();

    // ---- publish stage-0 partials; barrier 1 (flagA, S1) ----
    if (wave == 0) {
        float ps = 0.f;
        #pragma unroll
        for (int w = 0; w < 8; ++w) ps += pcol[w][lane];
        slot_store(&slots[(size_t)(0 * NB + b) * DIM + lane], ps);
        asm volatile("s_waitcnt vmcnt(0)" ::: "memory");
        if (lane == 0) flag_store(&flagA[b * 16], S1);
        poll_all(flagA, S1, lane);
    }
    __syncthreads();

    // ---- rounds 2..4 ----
    #pragma unroll 1
    for (int r = 0; r < 3; ++r) {
        // wave w sums 16 blocks' partials for dim `lane`
        {
            float s = 0.f;
            #pragma unroll
            for (int j = 0; j < 16; ++j)
                s += slot_load(&slots[(size_t)(r * NB + wave * 16 + j) * DIM + lane]);
            part[wave][lane] = s;
        }
        __syncthreads();
        // wave w: qs partial over e in [8w, 8w+8)
        {
            float qp = 0.f;
            #pragma unroll
            for (int k = 0; k < 8; ++k) {
                const int e = wave * 8 + k;
                const float se = part[0][e] + part[1][e] + part[2][e] + part[3][e]
                               + part[4][e] + part[5][e] + part[6][e] + part[7][e];
                qp += w2t[e * 65 + lane] * se;
            }
            part2[wave][lane] = qp;
        }
        __syncthreads();
        const float q = part2[0][lane] + part2[1][lane] + part2[2][lane] + part2[3][lane]
                      + part2[4][lane] + part2[5][lane] + part2[6][lane] + part2[7][lane];
        // u' = relu(base + qs - W2 @ u_self)   (uloc row is wave-local: safe)
        float acc = 0.f;
        #pragma unroll 8
        for (int e = 0; e < DIM; ++e)
            acc += w2t[e * 65 + lane] * uloc[wave * DIM + e];
        ur = fmaxf(br + q - acc, 0.f);
        uloc[wave * DIM + lane] = ur;
        pcol[wave][lane] = ur;

        // round 4: owner wave publishes u4[v]
        if (r == 2 && b == (v >> 3) && wave == (v & 7)) {
            slot_store(&uvg[lane], ur);
            asm volatile("s_waitcnt vmcnt(0)" ::: "memory");
        }
        __syncthreads();

        // publish stage r+1; barrier r+2
        if (wave == 0) {
            float ps = 0.f;
            #pragma unroll
            for (int w = 0; w < 8; ++w) ps += pcol[w][lane];
            slot_store(&slots[(size_t)((r + 1) * NB + b) * DIM + lane], ps);
            asm volatile("s_waitcnt vmcnt(0)" ::: "memory");
        }
        if (r == 0) {           // barrier 2: flagB, S2
            if (wave == 0) {
                if (lane == 0) flag_store(&flagB[b * 16], S2);
                poll_all(flagB, S2, lane);
            }
            __syncthreads();
        } else if (r == 1) {    // barrier 3: flagA, S3 (reuse distance 2 -> safe)
            if (wave == 0) {
                if (lane == 0) flag_store(&flagA[b * 16], S3);
                poll_all(flagA, S3, lane);
            }
            __syncthreads();
        }
        // r == 2: barrier 4 handled below (arrive-only for b != 0)
    }

    // ---- barrier 4 (flagB, S4): arrive; only block 0 waits ----
    if (wave == 0 && lane == 0) flag_store(&flagB[b * 16], S4);
    if (b != 0) return;
    if (wave == 0) poll_all(flagB, S4, lane);
    __syncthreads();

    // ---- final: block 0 ----
    {
        float s = 0.f;
        #pragma unroll
        for (int j = 0; j < 16; ++j)
            s += slot_load(&slots[(size_t)(3 * NB + wave * 16 + j) * DIM + lane]);
        part[wave][lane] = s;
    }
    __syncthreads();
    if (t < DIM) {
        su[t] = part[0][t] + part[1][t] + part[2][t] + part[3][t]
              + part[4][t] + part[5][t] + part[6][t] + part[7][t];
        uv[t] = slot_load(&uvg[t]);
    }
    __syncthreads();
    if (t < DIM) {
        float h1 = 0.f, h2 = 0.f;
        const float* w6r = W6 + t * DIM;
        const float* w7r = W7 + t * DIM;
        #pragma unroll 8
        for (int e = 0; e < DIM; ++e) {
            h1 += w6r[e] * su[e];
            h2 += w7r[e] * uv[e];
        }
        float val = W5[t] * fmaxf(h1, 0.f) + W5[DIM + t] * fmaxf(h2, 0.f);
        #pragma unroll
        for (int m = 32; m >= 1; m >>= 1) val += __shfl_xor(val, m, 64);
        if (t == 0) out[0] = val;
    }
}

extern "C" void kernel_launch(void* const* d_in, const int* in_sizes, int n_in,
                              void* d_out, int out_size, void* d_ws, size_t ws_size,
                              hipStream_t stream) {
    const float* x     = (const float*)d_in[0];
    const float* graph = (const float*)d_in[1];
    const float* W1    = (const float*)d_in[2];
    const float* W2    = (const float*)d_in[3];
    const float* W3    = (const float*)d_in[4];
    const float* W4    = (const float*)d_in[5];
    const float* W5    = (const float*)d_in[6];
    const float* W6    = (const float*)d_in[7];
    const float* W7    = (const float*)d_in[8];
    const int*   vptr  = (const int*)d_in[9];
    float* out = (float*)d_out;

    unsigned char* ws = (unsigned char*)d_ws;
    u32* flagA = (u32*)ws;                          // 128*16 u32 = 8 KB
    u32* flagB = (u32*)(ws + 8192);                 // 8 KB
    u32* slots = (u32*)(ws + 16384);                // 4*128*64*4 = 128 KB
    u32* uvg   = (u32*)(ws + 16384 + 131072);       // 256 B

    s2v<<<NB, NT, 0, stream>>>(x, graph, W1, W2, W3, W4, W5, W6, W7,
                               vptr, out, flagA, flagB, slots, uvg);
}